// Round 1
// baseline (237.120 us; speedup 1.0000x reference)
//
#include <hip/hip_runtime.h>
#include <hip/hip_bf16.h>

// Problem constants (GCN_66649302499531)
#define NN 20000
#define NG 400
#define D_IN 128
#define H1 256
#define H2 256
#define D_OUT 128
#define NB_RANK ((NN + 255) / 256)   // 79

// ---------------------------------------------------------------------------
// Rank / permutation kernels.
// rank[j] = #{i<j : idx[i]==idx[j]};  deg[j]=rank[j]+1;  dis[j]=rsqrt(deg[j])
// perm: nodes sorted by (group, index) so each group's members are contiguous
// in index order -> aggregation becomes a segmented prefix sum.
// ---------------------------------------------------------------------------

__global__ __launch_bounds__(256) void rank1_kernel(
    const int* __restrict__ idx, int* __restrict__ lrank,
    int* __restrict__ blockhist, int n)
{
    __shared__ int sg[256];
    __shared__ int hist[NG];
    int t = threadIdx.x;
    int b = blockIdx.x;
    int j = b * 256 + t;
    for (int g = t; g < NG; g += 256) hist[g] = 0;
    int g = (j < n) ? idx[j] : -1;
    sg[t] = g;
    __syncthreads();
    if (g >= 0) atomicAdd(&hist[g], 1);
    // stable local rank within this 256-node chunk
    int r = 0;
    for (int s = 0; s < t; ++s) {
        if (sg[s] == g) r++;
    }
    __syncthreads();   // hist complete
    if (j < n) lrank[j] = r;
    for (int gg = t; gg < NG; gg += 256) blockhist[b * NG + gg] = hist[gg];
}

__global__ __launch_bounds__(512) void rank2_kernel(
    const int* __restrict__ blockhist, int* __restrict__ blockoff,
    int* __restrict__ gs, int nb)
{
    __shared__ int tot[NG];
    int g = threadIdx.x;
    if (g < NG) {
        int run = 0;
        for (int b = 0; b < nb; ++b) {
            int v = blockhist[b * NG + g];
            blockoff[b * NG + g] = run;
            run += v;
        }
        tot[g] = run;
    }
    __syncthreads();
    if (threadIdx.x == 0) {
        int run = 0;
        for (int gg = 0; gg < NG; ++gg) { gs[gg] = run; run += tot[gg]; }
        gs[NG] = run;
    }
}

__global__ __launch_bounds__(256) void rank3_kernel(
    const int* __restrict__ idx, const int* __restrict__ lrank,
    const int* __restrict__ blockoff, const int* __restrict__ gs,
    float* __restrict__ dis, int* __restrict__ perm, int n)
{
    int j = blockIdx.x * 256 + threadIdx.x;
    if (j >= n) return;
    int g = idx[j];
    int r = blockoff[blockIdx.x * NG + g] + lrank[j];
    dis[j] = rsqrtf((float)(r + 1));
    perm[gs[g] + r] = j;
}

// ---------------------------------------------------------------------------
// Segmented prefix aggregation: one block per group, blockDim.x == C columns.
// out[j] = dis[j] * cumsum_{i<=j in group}(in[i]*dis[i])  (+bias, relu opt.)
// ---------------------------------------------------------------------------

#define AGG_CHUNK 1024

__global__ void agg_kernel(
    const float* __restrict__ in, float* __restrict__ out, int C,
    const float* __restrict__ bias, int relu,
    const float* __restrict__ dis, const int* __restrict__ perm,
    const int* __restrict__ gs)
{
    __shared__ int   sp[AGG_CHUNK];
    __shared__ float sd[AGG_CHUNK];
    int g = blockIdx.x;
    int s = gs[g], e = gs[g + 1];
    int cnt = e - s;
    int c = threadIdx.x;
    float bv = bias ? bias[c] : 0.0f;
    float acc = 0.0f;
    for (int base = 0; base < cnt; base += AGG_CHUNK) {
        int m = min(AGG_CHUNK, cnt - base);
        for (int k = c; k < m; k += blockDim.x) {
            int nidx = perm[s + base + k];
            sp[k] = nidx;
            sd[k] = dis[nidx];
        }
        __syncthreads();
        for (int k = 0; k < m; ++k) {
            int nidx = sp[k];
            float dn = sd[k];
            acc += in[(size_t)nidx * C + c] * dn;
            float o = acc * dn;
            if (bias) o += bv;
            if (relu) o = fmaxf(o, 0.0f);
            out[(size_t)nidx * C + c] = o;
        }
        __syncthreads();
    }
}

// ---------------------------------------------------------------------------
// fp32 GEMM: C[M,N] = A[M,K] @ B[K,N] (+bias, relu when fuse=1)
// 64x64 tile, TK=16, 256 threads, 4x4 micro-tile per thread.
// ---------------------------------------------------------------------------

#define TM 64
#define TN 64
#define TK 16

__global__ __launch_bounds__(256) void gemm_kernel(
    const float* __restrict__ A, const float* __restrict__ B,
    const float* __restrict__ bias, float* __restrict__ C,
    int M, int N, int K, int fuse)
{
    __shared__ float As[TK][TM + 4];   // [k][m]
    __shared__ float Bs[TK][TN + 4];   // [k][n]
    int tid = threadIdx.x;
    int tx = tid & 15, ty = tid >> 4;
    int m0 = blockIdx.x * TM;
    int n0 = blockIdx.y * TN;

    int lar = tid >> 2;           // A: row within tile (0..63)
    int lak = (tid & 3) * 4;      // A: k offset (0,4,8,12)
    int lbk = tid >> 4;           // B: k row (0..15)
    int lbn = (tid & 15) * 4;     // B: col offset

    float acc[4][4];
#pragma unroll
    for (int i = 0; i < 4; ++i)
#pragma unroll
        for (int j = 0; j < 4; ++j) acc[i][j] = 0.0f;

    for (int kt = 0; kt < K; kt += TK) {
        float4 av = make_float4(0.f, 0.f, 0.f, 0.f);
        int ar = m0 + lar;
        if (ar < M) av = *(const float4*)(A + (size_t)ar * K + kt + lak);
        float4 bvv = *(const float4*)(B + (size_t)(kt + lbk) * N + n0 + lbn);
        __syncthreads();
        As[lak + 0][lar] = av.x;
        As[lak + 1][lar] = av.y;
        As[lak + 2][lar] = av.z;
        As[lak + 3][lar] = av.w;
        *(float4*)&Bs[lbk][lbn] = bvv;
        __syncthreads();
#pragma unroll
        for (int k = 0; k < TK; ++k) {
            float4 a = *(const float4*)&As[k][ty * 4];
            float4 bq = *(const float4*)&Bs[k][tx * 4];
            acc[0][0] += a.x * bq.x; acc[0][1] += a.x * bq.y;
            acc[0][2] += a.x * bq.z; acc[0][3] += a.x * bq.w;
            acc[1][0] += a.y * bq.x; acc[1][1] += a.y * bq.y;
            acc[1][2] += a.y * bq.z; acc[1][3] += a.y * bq.w;
            acc[2][0] += a.z * bq.x; acc[2][1] += a.z * bq.y;
            acc[2][2] += a.z * bq.z; acc[2][3] += a.z * bq.w;
            acc[3][0] += a.w * bq.x; acc[3][1] += a.w * bq.y;
            acc[3][2] += a.w * bq.z; acc[3][3] += a.w * bq.w;
        }
    }

    int nbase = n0 + tx * 4;
    float4 bias4 = make_float4(0.f, 0.f, 0.f, 0.f);
    if (fuse) bias4 = *(const float4*)(bias + nbase);
#pragma unroll
    for (int i = 0; i < 4; ++i) {
        int row = m0 + ty * 4 + i;
        if (row < M) {
            float4 o;
            o.x = acc[i][0] + bias4.x;
            o.y = acc[i][1] + bias4.y;
            o.z = acc[i][2] + bias4.z;
            o.w = acc[i][3] + bias4.w;
            if (fuse) {
                o.x = fmaxf(o.x, 0.f); o.y = fmaxf(o.y, 0.f);
                o.z = fmaxf(o.z, 0.f); o.w = fmaxf(o.w, 0.f);
            }
            *(float4*)(C + (size_t)row * N + nbase) = o;
        }
    }
}

// ---------------------------------------------------------------------------
// LayerNorm over last dim (128). One wave (64 lanes) per row, 4 rows/block.
// ---------------------------------------------------------------------------

__global__ __launch_bounds__(256) void ln_kernel(
    const float* __restrict__ in, const float* __restrict__ gamma,
    const float* __restrict__ beta, float* __restrict__ out, int n)
{
    int lane = threadIdx.x & 63;
    int wave = threadIdx.x >> 6;
    int row = blockIdx.x * 4 + wave;
    if (row >= n) return;
    const float* p = in + (size_t)row * D_OUT;
    float2 v = *(const float2*)(p + lane * 2);
    float s1 = v.x + v.y;
    float s2 = v.x * v.x + v.y * v.y;
#pragma unroll
    for (int off = 32; off > 0; off >>= 1) {
        s1 += __shfl_down(s1, off);
        s2 += __shfl_down(s2, off);
    }
    s1 = __shfl(s1, 0);
    s2 = __shfl(s2, 0);
    float mu = s1 * (1.0f / D_OUT);
    float var = s2 * (1.0f / D_OUT) - mu * mu;
    float rstd = rsqrtf(var + 1e-5f);
    float2 gm = *(const float2*)(gamma + lane * 2);
    float2 bt = *(const float2*)(beta + lane * 2);
    float2 o;
    o.x = (v.x - mu) * rstd * gm.x + bt.x;
    o.y = (v.y - mu) * rstd * gm.y + bt.y;
    *(float2*)(out + (size_t)row * D_OUT + lane * 2) = o;
}

// ---------------------------------------------------------------------------

extern "C" void kernel_launch(void* const* d_in, const int* in_sizes, int n_in,
                              void* d_out, int out_size, void* d_ws, size_t ws_size,
                              hipStream_t stream) {
    const float* x     = (const float*)d_in[0];
    const int*   idx   = (const int*)d_in[1];
    const float* W1    = (const float*)d_in[2];
    const float* b1    = (const float*)d_in[3];
    const float* W2    = (const float*)d_in[4];
    const float* b2    = (const float*)d_in[5];
    const float* W3    = (const float*)d_in[6];
    const float* b3    = (const float*)d_in[7];
    const float* gamma = (const float*)d_in[8];
    const float* beta  = (const float*)d_in[9];
    float* out = (float*)d_out;

    char* ws = (char*)d_ws;
    size_t off = 0;
    auto alloc = [&](size_t bytes) -> void* {
        void* p = (void*)(ws + off);
        off += (bytes + 255) & ~(size_t)255;
        return p;
    };
    float* dis      = (float*)alloc(NN * sizeof(float));
    int*   perm     = (int*)alloc(NN * sizeof(int));
    int*   lrank    = (int*)alloc(NN * sizeof(int));
    int*   gs       = (int*)alloc((NG + 1) * sizeof(int));
    int*   bhist    = (int*)alloc(NB_RANK * NG * sizeof(int));
    int*   boff     = (int*)alloc(NB_RANK * NG * sizeof(int));
    float* bufA     = (float*)alloc((size_t)NN * 256 * sizeof(float));
    float* bufB     = (float*)alloc((size_t)NN * 256 * sizeof(float));

    // --- graph structure: ranks, dis, group-sorted permutation ---
    rank1_kernel<<<NB_RANK, 256, 0, stream>>>(idx, lrank, bhist, NN);
    rank2_kernel<<<1, 512, 0, stream>>>(bhist, boff, gs, NB_RANK);
    rank3_kernel<<<NB_RANK, 256, 0, stream>>>(idx, lrank, boff, gs, dis, perm, NN);

    // --- layer 1: h1 = relu(Agg(x) @ W1 + b1)   (Agg commutes with @W) ---
    agg_kernel<<<NG, D_IN, 0, stream>>>(x, bufA, D_IN, nullptr, 0, dis, perm, gs);
    {
        dim3 grid((NN + TM - 1) / TM, H1 / TN);
        gemm_kernel<<<grid, 256, 0, stream>>>(bufA, W1, b1, bufB, NN, H1, D_IN, 1);
    }

    // --- layer 2: h2 = relu(Agg(h1) @ W2 + b2) ---
    agg_kernel<<<NG, H1, 0, stream>>>(bufB, bufA, H1, nullptr, 0, dis, perm, gs);
    {
        dim3 grid((NN + TM - 1) / TM, H2 / TN);
        gemm_kernel<<<grid, 256, 0, stream>>>(bufA, W2, b2, bufB, NN, H2, H1, 1);
    }

    // --- layer 3: h3 = relu(Agg(h2 @ W3) + b3)  (GEMM first: fewer agg cols) ---
    {
        dim3 grid((NN + TM - 1) / TM, D_OUT / TN);
        gemm_kernel<<<grid, 256, 0, stream>>>(bufB, W3, nullptr, bufA, NN, D_OUT, H2, 0);
    }
    agg_kernel<<<NG, D_OUT, 0, stream>>>(bufA, bufB, D_OUT, b3, 1, dis, perm, gs);

    // --- final LayerNorm ---
    ln_kernel<<<(NN + 3) / 4, 256, 0, stream>>>(bufB, gamma, beta, out, NN);
}

// Round 2
// 231.534 us; speedup vs baseline: 1.0241x; 1.0241x over previous
//
#include <hip/hip_runtime.h>
#include <hip/hip_bf16.h>

// Problem constants (GCN_66649302499531)
#define NN 20000
#define NG 400
#define D_IN 128
#define H1 256
#define H2 256
#define D_OUT 128
#define NB_RANK ((NN + 255) / 256)   // 79

typedef __attribute__((ext_vector_type(8))) short short8;
typedef __attribute__((ext_vector_type(4))) float floatx4;

// ---------------------------------------------------------------------------
// Rank / permutation kernels.
// rank[j] = #{i<j : idx[i]==idx[j]};  deg[j]=rank[j]+1;  dis[j]=rsqrt(deg[j])
// perm: nodes sorted by (group, index) -> aggregation is a segmented prefix.
// ---------------------------------------------------------------------------

__global__ __launch_bounds__(256) void rank1_kernel(
    const int* __restrict__ idx, int* __restrict__ lrank,
    int* __restrict__ blockhist, int n)
{
    __shared__ int sg[256];
    __shared__ int hist[NG];
    int t = threadIdx.x;
    int b = blockIdx.x;
    int j = b * 256 + t;
    for (int g = t; g < NG; g += 256) hist[g] = 0;
    int g = (j < n) ? idx[j] : -1;
    sg[t] = g;
    __syncthreads();
    if (g >= 0) atomicAdd(&hist[g], 1);
    int r = 0;
    for (int s = 0; s < t; ++s) {
        if (sg[s] == g) r++;
    }
    __syncthreads();
    if (j < n) lrank[j] = r;
    for (int gg = t; gg < NG; gg += 256) blockhist[b * NG + gg] = hist[gg];
}

__global__ __launch_bounds__(512) void rank2_kernel(
    const int* __restrict__ blockhist, int* __restrict__ blockoff,
    int* __restrict__ gs, int nb)
{
    __shared__ int tot[NG];
    int g = threadIdx.x;
    if (g < NG) {
        int run = 0;
        for (int b = 0; b < nb; ++b) {
            int v = blockhist[b * NG + g];
            blockoff[b * NG + g] = run;
            run += v;
        }
        tot[g] = run;
    }
    __syncthreads();
    if (threadIdx.x == 0) {
        int run = 0;
        for (int gg = 0; gg < NG; ++gg) { gs[gg] = run; run += tot[gg]; }
        gs[NG] = run;
    }
}

__global__ __launch_bounds__(256) void rank3_kernel(
    const int* __restrict__ idx, const int* __restrict__ lrank,
    const int* __restrict__ blockoff, const int* __restrict__ gs,
    float* __restrict__ dis, int* __restrict__ perm, int n)
{
    int j = blockIdx.x * 256 + threadIdx.x;
    if (j >= n) return;
    int g = idx[j];
    int r = blockoff[blockIdx.x * NG + g] + lrank[j];
    dis[j] = rsqrtf((float)(r + 1));
    perm[gs[g] + r] = j;
}

// ---------------------------------------------------------------------------
// Weight transpose + bf16 convert: Wt[n*K + k] = bf16(W[k*N + n])
// ---------------------------------------------------------------------------

__global__ __launch_bounds__(256) void wt_kernel(
    const float* __restrict__ W, __hip_bfloat16* __restrict__ Wt, int K, int N)
{
    int o = blockIdx.x * 256 + threadIdx.x;
    if (o >= K * N) return;
    int n = o / K, k = o - n * K;
    Wt[o] = __float2bfloat16(W[(size_t)k * N + n]);
}

// ---------------------------------------------------------------------------
// Segmented prefix aggregation. Grid (NG, C/128), block 128.
// out[j] = dis[j] * cumsum_{i<=j in group}(in[i]*dis[i])  (+bias, relu opt.)
// fp32 accumulation; templated in/out dtype.
// ---------------------------------------------------------------------------

#define AGG_CHUNK 1024

__device__ __forceinline__ float ldf(const float* p) { return *p; }
__device__ __forceinline__ float ldf(const __hip_bfloat16* p) { return __bfloat162float(*p); }
__device__ __forceinline__ void stf(float* p, float v) { *p = v; }
__device__ __forceinline__ void stf(__hip_bfloat16* p, float v) { *p = __float2bfloat16(v); }

template <typename TIN, typename TOUT>
__global__ __launch_bounds__(128) void agg_kernel(
    const TIN* __restrict__ in, TOUT* __restrict__ out, int C,
    const float* __restrict__ bias, int relu,
    const float* __restrict__ dis, const int* __restrict__ perm,
    const int* __restrict__ gs)
{
    __shared__ int   sp[AGG_CHUNK];
    __shared__ float sd[AGG_CHUNK];
    int g = blockIdx.x;
    int s = gs[g], e = gs[g + 1];
    int cnt = e - s;
    if (cnt <= 0) return;
    int c = blockIdx.y * 128 + threadIdx.x;
    float bv = bias ? bias[c] : 0.0f;
    float acc = 0.0f;
    for (int base = 0; base < cnt; base += AGG_CHUNK) {
        int m = min(AGG_CHUNK, cnt - base);
        for (int k = threadIdx.x; k < m; k += 128) {
            int nidx = perm[s + base + k];
            sp[k] = nidx;
            sd[k] = dis[nidx];
        }
        __syncthreads();
        // software-pipelined prefix: prefetch next member while processing cur
        float vcur = ldf(in + (size_t)sp[0] * C + c);
        for (int k = 0; k < m; ++k) {
            float vnext = (k + 1 < m) ? ldf(in + (size_t)sp[k + 1] * C + c) : 0.0f;
            float dn = sd[k];
            acc += vcur * dn;
            float o = acc * dn + bv;
            if (relu) o = fmaxf(o, 0.0f);
            stf(out + (size_t)sp[k] * C + c, o);
            vcur = vnext;
        }
        __syncthreads();
    }
}

// ---------------------------------------------------------------------------
// bf16 MFMA GEMM: C[M,N] = A[M,K] @ Wt[N,K]^T (+bias,relu if fuse)
// A row-major bf16, Wt row-major-by-N bf16 (pre-transposed weight).
// 128x128 block tile, BK=64, 256 threads = 4 waves in 2x2, each wave 64x64
// = 4x4 MFMA tiles (16x16x32), fp32 accumulate. Output bf16.
// ---------------------------------------------------------------------------

#define GBM 128
#define GBN 128
#define GBK 64
#define LDK 72   // padded LDS stride (elems): +8 bf16 = 16B -> 2-way bank alias (free)

__global__ __launch_bounds__(256) void gemm_mfma(
    const __hip_bfloat16* __restrict__ A, const __hip_bfloat16* __restrict__ Bt,
    const float* __restrict__ bias, __hip_bfloat16* __restrict__ C,
    int M, int N, int K, int fuse)
{
    __shared__ short As[GBM * LDK];
    __shared__ short Bs[GBN * LDK];

    int tid = threadIdx.x;
    int wave = tid >> 6;
    int lane = tid & 63;
    int quad = lane >> 4;
    int l15 = lane & 15;
    int m0 = blockIdx.x * GBM;
    int n0 = blockIdx.y * GBN;
    int mw = (wave & 1) * 64;
    int nw = (wave >> 1) * 64;

    int sr = tid >> 3;           // staging row 0..31 (x4 reps of 32)
    int sc = (tid & 7) * 8;      // staging elem offset within 64-elem k-slice

    floatx4 acc[4][4];
#pragma unroll
    for (int i = 0; i < 4; ++i)
#pragma unroll
        for (int j = 0; j < 4; ++j) acc[i][j] = (floatx4)0.0f;

    const short8 zero8 = {0, 0, 0, 0, 0, 0, 0, 0};

    for (int kt = 0; kt < K; kt += GBK) {
        short8 av[4], bv[4];
#pragma unroll
        for (int r = 0; r < 4; ++r) {
            int row = sr + r * 32;
            int gm = m0 + row;
            av[r] = (gm < M)
                ? *(const short8*)((const short*)A + (size_t)gm * K + kt + sc)
                : zero8;
            int gn = n0 + row;   // N is a multiple of 128, always valid
            bv[r] = *(const short8*)((const short*)Bt + (size_t)gn * K + kt + sc);
        }
        __syncthreads();   // protect previous iteration's LDS reads
#pragma unroll
        for (int r = 0; r < 4; ++r) {
            *(short8*)&As[(sr + r * 32) * LDK + sc] = av[r];
            *(short8*)&Bs[(sr + r * 32) * LDK + sc] = bv[r];
        }
        __syncthreads();
#pragma unroll
        for (int kk = 0; kk < GBK; kk += 32) {
            short8 af[4], bf[4];
#pragma unroll
            for (int i = 0; i < 4; ++i)
                af[i] = *(const short8*)&As[(mw + i * 16 + l15) * LDK + kk + quad * 8];
#pragma unroll
            for (int j = 0; j < 4; ++j)
                bf[j] = *(const short8*)&Bs[(nw + j * 16 + l15) * LDK + kk + quad * 8];
#pragma unroll
            for (int i = 0; i < 4; ++i)
#pragma unroll
                for (int j = 0; j < 4; ++j)
                    acc[i][j] = __builtin_amdgcn_mfma_f32_16x16x32_bf16(
                        af[i], bf[j], acc[i][j], 0, 0, 0);
        }
    }

    // epilogue: D[row=quad*4+r][col=lane&15] per 16x16 tile
    float bj[4];
#pragma unroll
    for (int j = 0; j < 4; ++j)
        bj[j] = fuse ? bias[n0 + nw + j * 16 + l15] : 0.0f;
#pragma unroll
    for (int i = 0; i < 4; ++i) {
#pragma unroll
        for (int r = 0; r < 4; ++r) {
            int grow = m0 + mw + i * 16 + quad * 4 + r;
            if (grow < M) {
#pragma unroll
                for (int j = 0; j < 4; ++j) {
                    float v = acc[i][j][r];
                    if (fuse) v = fmaxf(v + bj[j], 0.0f);
                    C[(size_t)grow * N + n0 + nw + j * 16 + l15] = __float2bfloat16(v);
                }
            }
        }
    }
}

// ---------------------------------------------------------------------------
// LayerNorm over last dim (128). One wave per row, 4 rows/block.
// ---------------------------------------------------------------------------

__global__ __launch_bounds__(256) void ln_kernel(
    const float* __restrict__ in, const float* __restrict__ gamma,
    const float* __restrict__ beta, float* __restrict__ out, int n)
{
    int lane = threadIdx.x & 63;
    int wave = threadIdx.x >> 6;
    int row = blockIdx.x * 4 + wave;
    if (row >= n) return;
    const float* p = in + (size_t)row * D_OUT;
    float2 v = *(const float2*)(p + lane * 2);
    float s1 = v.x + v.y;
    float s2 = v.x * v.x + v.y * v.y;
#pragma unroll
    for (int off = 32; off > 0; off >>= 1) {
        s1 += __shfl_down(s1, off);
        s2 += __shfl_down(s2, off);
    }
    s1 = __shfl(s1, 0);
    s2 = __shfl(s2, 0);
    float mu = s1 * (1.0f / D_OUT);
    float var = s2 * (1.0f / D_OUT) - mu * mu;
    float rstd = rsqrtf(var + 1e-5f);
    float2 gm = *(const float2*)(gamma + lane * 2);
    float2 bt = *(const float2*)(beta + lane * 2);
    float2 o;
    o.x = (v.x - mu) * rstd * gm.x + bt.x;
    o.y = (v.y - mu) * rstd * gm.y + bt.y;
    *(float2*)(out + (size_t)row * D_OUT + lane * 2) = o;
}

// ---------------------------------------------------------------------------

extern "C" void kernel_launch(void* const* d_in, const int* in_sizes, int n_in,
                              void* d_out, int out_size, void* d_ws, size_t ws_size,
                              hipStream_t stream) {
    const float* x     = (const float*)d_in[0];
    const int*   idx   = (const int*)d_in[1];
    const float* W1    = (const float*)d_in[2];
    const float* b1    = (const float*)d_in[3];
    const float* W2    = (const float*)d_in[4];
    const float* b2    = (const float*)d_in[5];
    const float* W3    = (const float*)d_in[6];
    const float* b3    = (const float*)d_in[7];
    const float* gamma = (const float*)d_in[8];
    const float* beta  = (const float*)d_in[9];
    float* out = (float*)d_out;

    char* ws = (char*)d_ws;
    size_t off = 0;
    auto alloc = [&](size_t bytes) -> void* {
        void* p = (void*)(ws + off);
        off += (bytes + 255) & ~(size_t)255;
        return p;
    };
    float* dis   = (float*)alloc(NN * sizeof(float));
    int*   perm  = (int*)alloc(NN * sizeof(int));
    int*   lrank = (int*)alloc(NN * sizeof(int));
    int*   gs    = (int*)alloc((NG + 1) * sizeof(int));
    int*   bhist = (int*)alloc(NB_RANK * NG * sizeof(int));
    int*   boff  = (int*)alloc(NB_RANK * NG * sizeof(int));
    __hip_bfloat16* Wt1 = (__hip_bfloat16*)alloc((size_t)D_IN * H1 * 2);
    __hip_bfloat16* Wt2 = (__hip_bfloat16*)alloc((size_t)H1 * H2 * 2);
    __hip_bfloat16* Wt3 = (__hip_bfloat16*)alloc((size_t)H2 * D_OUT * 2);
    __hip_bfloat16* bufA = (__hip_bfloat16*)alloc((size_t)NN * 256 * 2);
    __hip_bfloat16* bufB = (__hip_bfloat16*)alloc((size_t)NN * 256 * 2);
    float* bufF = (float*)alloc((size_t)NN * D_OUT * sizeof(float));

    // --- graph structure ---
    rank1_kernel<<<NB_RANK, 256, 0, stream>>>(idx, lrank, bhist, NN);
    rank2_kernel<<<1, 512, 0, stream>>>(bhist, boff, gs, NB_RANK);
    rank3_kernel<<<NB_RANK, 256, 0, stream>>>(idx, lrank, boff, gs, dis, perm, NN);

    // --- weights -> bf16 transposed [N][K] ---
    wt_kernel<<<(D_IN * H1 + 255) / 256, 256, 0, stream>>>(W1, Wt1, D_IN, H1);
    wt_kernel<<<(H1 * H2 + 255) / 256, 256, 0, stream>>>(W2, Wt2, H1, H2);
    wt_kernel<<<(H2 * D_OUT + 255) / 256, 256, 0, stream>>>(W3, Wt3, H2, D_OUT);

    // --- layer 1: h1 = relu(Agg(x) @ W1 + b1) ---
    {
        dim3 ag(NG, D_IN / 128);
        agg_kernel<float, __hip_bfloat16><<<ag, 128, 0, stream>>>(
            x, bufA, D_IN, nullptr, 0, dis, perm, gs);
        dim3 grid((NN + GBM - 1) / GBM, H1 / GBN);
        gemm_mfma<<<grid, 256, 0, stream>>>(bufA, Wt1, b1, bufB, NN, H1, D_IN, 1);
    }
    // --- layer 2: h2 = relu(Agg(h1) @ W2 + b2) ---
    {
        dim3 ag(NG, H1 / 128);
        agg_kernel<__hip_bfloat16, __hip_bfloat16><<<ag, 128, 0, stream>>>(
            bufB, bufA, H1, nullptr, 0, dis, perm, gs);
        dim3 grid((NN + GBM - 1) / GBM, H2 / GBN);
        gemm_mfma<<<grid, 256, 0, stream>>>(bufA, Wt2, b2, bufB, NN, H2, H1, 1);
    }
    // --- layer 3: h3 = relu(Agg(h2 @ W3) + b3) ---
    {
        dim3 grid((NN + GBM - 1) / GBM, D_OUT / GBN);
        gemm_mfma<<<grid, 256, 0, stream>>>(bufB, Wt3, nullptr, bufA, NN, D_OUT, H2, 0);
        dim3 ag(NG, D_OUT / 128);
        agg_kernel<__hip_bfloat16, float><<<ag, 128, 0, stream>>>(
            bufA, bufF, D_OUT, b3, 1, dis, perm, gs);
    }
    // --- final LayerNorm ---
    ln_kernel<<<(NN + 3) / 4, 256, 0, stream>>>(bufF, gamma, beta, out, NN);
}

// Round 3
// 201.377 us; speedup vs baseline: 1.1775x; 1.1498x over previous
//
#include <hip/hip_runtime.h>
#include <hip/hip_bf16.h>

// Problem constants (GCN_66649302499531)
#define NN 20000
#define NG 400
#define D_IN 128
#define H1 256
#define H2 256
#define D_OUT 128
#define NB_RANK ((NN + 255) / 256)   // 79
#define NB_PAD 80                    // padded stride for per-group block hists

typedef __attribute__((ext_vector_type(8))) short short8;
typedef __attribute__((ext_vector_type(4))) float floatx4;

// ---------------------------------------------------------------------------
// Rank / permutation kernels.
// rank[j] = #{i<j : idx[i]==idx[j]};  deg[j]=rank[j]+1;  dis[j]=rsqrt(deg[j])
// perm: nodes sorted by (group, index) -> aggregation is a segmented prefix.
// ---------------------------------------------------------------------------

__global__ __launch_bounds__(256) void rank1_kernel(
    const int* __restrict__ idx, int* __restrict__ lrank,
    int* __restrict__ blockhist, int n)
{
    __shared__ int sg[256];
    __shared__ int hist[NG];
    int t = threadIdx.x;
    int b = blockIdx.x;
    int j = b * 256 + t;
    for (int g = t; g < NG; g += 256) hist[g] = 0;
    int g = (j < n) ? idx[j] : -1;
    sg[t] = g;
    __syncthreads();
    if (g >= 0) atomicAdd(&hist[g], 1);
    int r = 0;
    for (int s = 0; s < t; ++s) {
        if (sg[s] == g) r++;
    }
    __syncthreads();
    if (j < n) lrank[j] = r;
    // transposed layout: blockhist[g][b], padded stride NB_PAD
    for (int gg = t; gg < NG; gg += 256) blockhist[gg * NB_PAD + b] = hist[gg];
}

// 512 threads: thread g scans its group's 79 block counts (batched int4
// prefetch -> register scan), then Hillis-Steele scan over group totals.
__global__ __launch_bounds__(512) void rank2_kernel(
    const int* __restrict__ blockhist, int* __restrict__ blockoff,
    int* __restrict__ gs)
{
    __shared__ int tot[512];
    int g = threadIdx.x;
    int run = 0;
    if (g < NG) {
        int4 buf[NB_PAD / 4];
        const int4* src = (const int4*)(blockhist + g * NB_PAD);
#pragma unroll
        for (int i = 0; i < NB_PAD / 4; ++i) buf[i] = src[i];   // parallel issue
        const int* bi = (const int*)buf;
#pragma unroll
        for (int b = 0; b < NB_RANK; ++b) {
            blockoff[g * NB_PAD + b] = run;
            run += bi[b];
        }
    }
    tot[threadIdx.x] = (g < NG) ? run : 0;
    __syncthreads();
    // inclusive Hillis-Steele scan over 512 slots
#pragma unroll
    for (int off = 1; off < 512; off <<= 1) {
        int v = (threadIdx.x >= off) ? tot[threadIdx.x - off] : 0;
        __syncthreads();
        tot[threadIdx.x] += v;
        __syncthreads();
    }
    if (threadIdx.x == 0) gs[0] = 0;
    if (threadIdx.x < NG) gs[threadIdx.x + 1] = tot[threadIdx.x];
}

__global__ __launch_bounds__(256) void rank3_kernel(
    const int* __restrict__ idx, const int* __restrict__ lrank,
    const int* __restrict__ blockoff, const int* __restrict__ gs,
    float* __restrict__ dis, int* __restrict__ perm, int n)
{
    int j = blockIdx.x * 256 + threadIdx.x;
    if (j >= n) return;
    int g = idx[j];
    int r = blockoff[g * NB_PAD + blockIdx.x] + lrank[j];
    dis[j] = rsqrtf((float)(r + 1));
    perm[gs[g] + r] = j;
}

// ---------------------------------------------------------------------------
// All three weight transposes (fp32 [K][N] -> bf16 [N][K]) in one launch.
// ---------------------------------------------------------------------------

__global__ __launch_bounds__(256) void wt_all(
    const float* __restrict__ W1, const float* __restrict__ W2,
    const float* __restrict__ W3, __hip_bfloat16* __restrict__ Wt1,
    __hip_bfloat16* __restrict__ Wt2, __hip_bfloat16* __restrict__ Wt3)
{
    int o = blockIdx.x * 256 + threadIdx.x;
    if (o < D_IN * H1) {                       // W1: K=128, N=256
        int n = o / D_IN, k = o - n * D_IN;
        Wt1[o] = __float2bfloat16(W1[(size_t)k * H1 + n]);
    } else if (o < D_IN * H1 + H1 * H2) {      // W2: K=256, N=256
        int p = o - D_IN * H1;
        int n = p / H1, k = p - n * H1;
        Wt2[p] = __float2bfloat16(W2[(size_t)k * H2 + n]);
    } else {                                   // W3: K=256, N=128
        int p = o - D_IN * H1 - H1 * H2;
        int n = p / H2, k = p - n * H2;
        Wt3[p] = __float2bfloat16(W3[(size_t)k * D_OUT + n]);
    }
}

// ---------------------------------------------------------------------------
// Segmented prefix aggregation, tile-batched.
// One block per group, blockDim.x == C (thread = column). Members processed
// in tiles of AGG_T: all tile loads issued in parallel into registers
// (coalesced over columns), then a register-resident serial scan + stores.
// out[j] = dis[j] * cumsum_{i<=j in group}(in[i]*dis[i])  (+bias, relu opt.)
// ---------------------------------------------------------------------------

#define AGG_T 32

__device__ __forceinline__ float ldf(const float* p) { return *p; }
__device__ __forceinline__ float ldf(const __hip_bfloat16* p) { return __bfloat162float(*p); }
__device__ __forceinline__ void stf(float* p, float v) { *p = v; }
__device__ __forceinline__ void stf(__hip_bfloat16* p, float v) { *p = __float2bfloat16(v); }

template <typename TIN, typename TOUT>
__global__ void agg_scan(
    const TIN* __restrict__ in, TOUT* __restrict__ out, int C,
    const float* __restrict__ bias, int relu,
    const float* __restrict__ dis, const int* __restrict__ perm,
    const int* __restrict__ gs)
{
    __shared__ int   sp[AGG_T];
    __shared__ float sd[AGG_T];
    int g = blockIdx.x;
    int s = gs[g], cnt = gs[g + 1] - s;
    int c = threadIdx.x;
    float bv = bias ? bias[c] : 0.0f;
    float acc = 0.0f;
    for (int base = 0; base < cnt; base += AGG_T) {
        int mt = min(AGG_T, cnt - base);
        __syncthreads();            // protect sp/sd from previous tile's readers
        if (c < mt) {
            int nidx = perm[s + base + c];
            sp[c] = nidx;
            sd[c] = dis[nidx];
        }
        __syncthreads();
        float v[AGG_T];
#pragma unroll
        for (int m = 0; m < AGG_T; ++m)
            v[m] = (m < mt) ? ldf(in + (size_t)sp[m] * C + c) : 0.0f;
#pragma unroll
        for (int m = 0; m < AGG_T; ++m) {
            if (m >= mt) break;
            float dn = sd[m];
            acc += v[m] * dn;
            float o = acc * dn + bv;
            if (relu) o = fmaxf(o, 0.0f);
            stf(out + (size_t)sp[m] * C + c, o);
        }
    }
}

// ---------------------------------------------------------------------------
// bf16 MFMA GEMM: C[M,N] = A[M,K] @ Wt[N,K]^T (+bias,relu if fuse)
// 128x128 block tile, BK=64, 256 threads = 4 waves in 2x2, each wave 64x64
// = 4x4 MFMA tiles (16x16x32), fp32 accumulate. Output bf16.
// ---------------------------------------------------------------------------

#define GBM 128
#define GBN 128
#define GBK 64
#define LDK 72   // padded LDS stride (elems): +8 bf16 = 16B -> 2-way bank alias (free)

__global__ __launch_bounds__(256) void gemm_mfma(
    const __hip_bfloat16* __restrict__ A, const __hip_bfloat16* __restrict__ Bt,
    const float* __restrict__ bias, __hip_bfloat16* __restrict__ C,
    int M, int N, int K, int fuse)
{
    __shared__ short As[GBM * LDK];
    __shared__ short Bs[GBN * LDK];

    int tid = threadIdx.x;
    int wave = tid >> 6;
    int lane = tid & 63;
    int quad = lane >> 4;
    int l15 = lane & 15;
    int m0 = blockIdx.x * GBM;
    int n0 = blockIdx.y * GBN;
    int mw = (wave & 1) * 64;
    int nw = (wave >> 1) * 64;

    int sr = tid >> 3;           // staging row 0..31 (x4 reps of 32)
    int sc = (tid & 7) * 8;      // staging elem offset within 64-elem k-slice

    floatx4 acc[4][4];
#pragma unroll
    for (int i = 0; i < 4; ++i)
#pragma unroll
        for (int j = 0; j < 4; ++j) acc[i][j] = (floatx4)0.0f;

    const short8 zero8 = {0, 0, 0, 0, 0, 0, 0, 0};

    for (int kt = 0; kt < K; kt += GBK) {
        short8 av[4], bv[4];
#pragma unroll
        for (int r = 0; r < 4; ++r) {
            int row = sr + r * 32;
            int gm = m0 + row;
            av[r] = (gm < M)
                ? *(const short8*)((const short*)A + (size_t)gm * K + kt + sc)
                : zero8;
            int gn = n0 + row;   // N multiple of 128, always valid
            bv[r] = *(const short8*)((const short*)Bt + (size_t)gn * K + kt + sc);
        }
        __syncthreads();   // protect previous iteration's LDS reads
#pragma unroll
        for (int r = 0; r < 4; ++r) {
            *(short8*)&As[(sr + r * 32) * LDK + sc] = av[r];
            *(short8*)&Bs[(sr + r * 32) * LDK + sc] = bv[r];
        }
        __syncthreads();
#pragma unroll
        for (int kk = 0; kk < GBK; kk += 32) {
            short8 af[4], bf[4];
#pragma unroll
            for (int i = 0; i < 4; ++i)
                af[i] = *(const short8*)&As[(mw + i * 16 + l15) * LDK + kk + quad * 8];
#pragma unroll
            for (int j = 0; j < 4; ++j)
                bf[j] = *(const short8*)&Bs[(nw + j * 16 + l15) * LDK + kk + quad * 8];
#pragma unroll
            for (int i = 0; i < 4; ++i)
#pragma unroll
                for (int j = 0; j < 4; ++j)
                    acc[i][j] = __builtin_amdgcn_mfma_f32_16x16x32_bf16(
                        af[i], bf[j], acc[i][j], 0, 0, 0);
        }
    }

    float bj[4];
#pragma unroll
    for (int j = 0; j < 4; ++j)
        bj[j] = fuse ? bias[n0 + nw + j * 16 + l15] : 0.0f;
#pragma unroll
    for (int i = 0; i < 4; ++i) {
#pragma unroll
        for (int r = 0; r < 4; ++r) {
            int grow = m0 + mw + i * 16 + quad * 4 + r;
            if (grow < M) {
#pragma unroll
                for (int j = 0; j < 4; ++j) {
                    float v = acc[i][j][r];
                    if (fuse) v = fmaxf(v + bj[j], 0.0f);
                    C[(size_t)grow * N + n0 + nw + j * 16 + l15] = __float2bfloat16(v);
                }
            }
        }
    }
}

// ---------------------------------------------------------------------------
// LayerNorm over last dim (128). One wave per row, 4 rows/block.
// ---------------------------------------------------------------------------

__global__ __launch_bounds__(256) void ln_kernel(
    const float* __restrict__ in, const float* __restrict__ gamma,
    const float* __restrict__ beta, float* __restrict__ out, int n)
{
    int lane = threadIdx.x & 63;
    int wave = threadIdx.x >> 6;
    int row = blockIdx.x * 4 + wave;
    if (row >= n) return;
    const float* p = in + (size_t)row * D_OUT;
    float2 v = *(const float2*)(p + lane * 2);
    float s1 = v.x + v.y;
    float s2 = v.x * v.x + v.y * v.y;
#pragma unroll
    for (int off = 32; off > 0; off >>= 1) {
        s1 += __shfl_down(s1, off);
        s2 += __shfl_down(s2, off);
    }
    s1 = __shfl(s1, 0);
    s2 = __shfl(s2, 0);
    float mu = s1 * (1.0f / D_OUT);
    float var = s2 * (1.0f / D_OUT) - mu * mu;
    float rstd = rsqrtf(var + 1e-5f);
    float2 gm = *(const float2*)(gamma + lane * 2);
    float2 bt = *(const float2*)(beta + lane * 2);
    float2 o;
    o.x = (v.x - mu) * rstd * gm.x + bt.x;
    o.y = (v.y - mu) * rstd * gm.y + bt.y;
    *(float2*)(out + (size_t)row * D_OUT + lane * 2) = o;
}

// ---------------------------------------------------------------------------

extern "C" void kernel_launch(void* const* d_in, const int* in_sizes, int n_in,
                              void* d_out, int out_size, void* d_ws, size_t ws_size,
                              hipStream_t stream) {
    const float* x     = (const float*)d_in[0];
    const int*   idx   = (const int*)d_in[1];
    const float* W1    = (const float*)d_in[2];
    const float* b1    = (const float*)d_in[3];
    const float* W2    = (const float*)d_in[4];
    const float* b2    = (const float*)d_in[5];
    const float* W3    = (const float*)d_in[6];
    const float* b3    = (const float*)d_in[7];
    const float* gamma = (const float*)d_in[8];
    const float* beta  = (const float*)d_in[9];
    float* out = (float*)d_out;

    char* ws = (char*)d_ws;
    size_t off = 0;
    auto alloc = [&](size_t bytes) -> void* {
        void* p = (void*)(ws + off);
        off += (bytes + 255) & ~(size_t)255;
        return p;
    };
    float* dis   = (float*)alloc(NN * sizeof(float));
    int*   perm  = (int*)alloc(NN * sizeof(int));
    int*   lrank = (int*)alloc(NN * sizeof(int));
    int*   gs    = (int*)alloc((NG + 1) * sizeof(int));
    int*   bhist = (int*)alloc(NG * NB_PAD * sizeof(int));
    int*   boff  = (int*)alloc(NG * NB_PAD * sizeof(int));
    __hip_bfloat16* Wt1 = (__hip_bfloat16*)alloc((size_t)D_IN * H1 * 2);
    __hip_bfloat16* Wt2 = (__hip_bfloat16*)alloc((size_t)H1 * H2 * 2);
    __hip_bfloat16* Wt3 = (__hip_bfloat16*)alloc((size_t)H2 * D_OUT * 2);
    __hip_bfloat16* bufA = (__hip_bfloat16*)alloc((size_t)NN * 256 * 2);
    __hip_bfloat16* bufB = (__hip_bfloat16*)alloc((size_t)NN * 256 * 2);
    float* bufF = (float*)alloc((size_t)NN * D_OUT * sizeof(float));

    // --- graph structure ---
    rank1_kernel<<<NB_RANK, 256, 0, stream>>>(idx, lrank, bhist, NN);
    rank2_kernel<<<1, 512, 0, stream>>>(bhist, boff, gs);
    rank3_kernel<<<NB_RANK, 256, 0, stream>>>(idx, lrank, boff, gs, dis, perm, NN);

    // --- weights -> bf16 transposed [N][K], one launch ---
    wt_all<<<(D_IN * H1 + H1 * H2 + H2 * D_OUT + 255) / 256, 256, 0, stream>>>(
        W1, W2, W3, Wt1, Wt2, Wt3);

    // --- layer 1: h1 = relu(Agg(x) @ W1 + b1) ---
    agg_scan<float, __hip_bfloat16><<<NG, D_IN, 0, stream>>>(
        x, bufA, D_IN, nullptr, 0, dis, perm, gs);
    {
        dim3 grid((NN + GBM - 1) / GBM, H1 / GBN);
        gemm_mfma<<<grid, 256, 0, stream>>>(bufA, Wt1, b1, bufB, NN, H1, D_IN, 1);
    }
    // --- layer 2: h2 = relu(Agg(h1) @ W2 + b2) ---
    agg_scan<__hip_bfloat16, __hip_bfloat16><<<NG, H1, 0, stream>>>(
        bufB, bufA, H1, nullptr, 0, dis, perm, gs);
    {
        dim3 grid((NN + GBM - 1) / GBM, H2 / GBN);
        gemm_mfma<<<grid, 256, 0, stream>>>(bufA, Wt2, b2, bufB, NN, H2, H1, 1);
    }
    // --- layer 3: h3 = relu(Agg(h2 @ W3) + b3) ---
    {
        dim3 grid((NN + GBM - 1) / GBM, D_OUT / GBN);
        gemm_mfma<<<grid, 256, 0, stream>>>(bufB, Wt3, nullptr, bufA, NN, D_OUT, H2, 0);
    }
    agg_scan<__hip_bfloat16, float><<<NG, D_OUT, 0, stream>>>(
        bufA, bufF, D_OUT, b3, 1, dis, perm, gs);

    // --- final LayerNorm ---
    ln_kernel<<<(NN + 3) / 4, 256, 0, stream>>>(bufF, gamma, beta, out, NN);
}

// Round 4
// 159.933 us; speedup vs baseline: 1.4826x; 1.2591x over previous
//
#include <hip/hip_runtime.h>
#include <hip/hip_bf16.h>

// Problem constants (GCN_66649302499531)
#define NN 20000
#define NG 400
#define D_IN 128
#define H1 256
#define H2 256
#define D_OUT 128
#define NB_RANK ((NN + 255) / 256)   // 79
#define NB_PAD 80

typedef __attribute__((ext_vector_type(8))) short short8;
typedef __attribute__((ext_vector_type(4))) float floatx4;

__device__ __forceinline__ short f2b(float f) {
    __hip_bfloat16 h = __float2bfloat16(f);
    return *(short*)&h;
}
__device__ __forceinline__ float b2f(short s) {
    __hip_bfloat16 h = *(__hip_bfloat16*)&s;
    return __bfloat162float(h);
}

// ---------------------------------------------------------------------------
// Rank / permutation kernels.
// rank[j] = #{i<j : idx[i]==idx[j]};  deg[j]=rank[j]+1;  dis[j]=rsqrt(deg[j])
// perm: nodes sorted by (group, index) -> aggregation is a segmented prefix.
// ---------------------------------------------------------------------------

__global__ __launch_bounds__(256) void rank1_kernel(
    const int* __restrict__ idx, int* __restrict__ lrank,
    int* __restrict__ blockhist, int n)
{
    __shared__ int sg[256];
    __shared__ int hist[NG];
    int t = threadIdx.x;
    int b = blockIdx.x;
    int j = b * 256 + t;
    for (int g = t; g < NG; g += 256) hist[g] = 0;
    int g = (j < n) ? idx[j] : -1;
    sg[t] = g;
    __syncthreads();
    if (g >= 0) atomicAdd(&hist[g], 1);
    int r = 0;
    for (int s = 0; s < t; ++s) {
        if (sg[s] == g) r++;
    }
    __syncthreads();
    if (j < n) lrank[j] = r;
    for (int gg = t; gg < NG; gg += 256) blockhist[gg * NB_PAD + b] = hist[gg];
}

__global__ __launch_bounds__(512) void rank2_kernel(
    const int* __restrict__ blockhist, int* __restrict__ blockoff,
    int* __restrict__ gs)
{
    __shared__ int tot[512];
    int g = threadIdx.x;
    int run = 0;
    if (g < NG) {
        int4 buf[NB_PAD / 4];
        const int4* src = (const int4*)(blockhist + g * NB_PAD);
#pragma unroll
        for (int i = 0; i < NB_PAD / 4; ++i) buf[i] = src[i];
        const int* bi = (const int*)buf;
#pragma unroll
        for (int b = 0; b < NB_RANK; ++b) {
            blockoff[g * NB_PAD + b] = run;
            run += bi[b];
        }
    }
    tot[threadIdx.x] = (g < NG) ? run : 0;
    __syncthreads();
#pragma unroll
    for (int off = 1; off < 512; off <<= 1) {
        int v = (threadIdx.x >= off) ? tot[threadIdx.x - off] : 0;
        __syncthreads();
        tot[threadIdx.x] += v;
        __syncthreads();
    }
    if (threadIdx.x == 0) gs[0] = 0;
    if (threadIdx.x < NG) gs[threadIdx.x + 1] = tot[threadIdx.x];
}

__global__ __launch_bounds__(256) void rank3_kernel(
    const int* __restrict__ idx, const int* __restrict__ lrank,
    const int* __restrict__ blockoff, const int* __restrict__ gs,
    float* __restrict__ dis, int* __restrict__ perm, int n)
{
    int j = blockIdx.x * 256 + threadIdx.x;
    if (j >= n) return;
    int g = idx[j];
    int r = blockoff[g * NB_PAD + blockIdx.x] + lrank[j];
    dis[j] = rsqrtf((float)(r + 1));
    perm[gs[g] + r] = j;
}

// ---------------------------------------------------------------------------
// All three weight transposes (fp32 [K][N] -> bf16 [N][K]) in one launch.
// ---------------------------------------------------------------------------

__global__ __launch_bounds__(256) void wt_all(
    const float* __restrict__ W1, const float* __restrict__ W2,
    const float* __restrict__ W3, __hip_bfloat16* __restrict__ Wt1,
    __hip_bfloat16* __restrict__ Wt2, __hip_bfloat16* __restrict__ Wt3)
{
    int o = blockIdx.x * 256 + threadIdx.x;
    if (o < D_IN * H1) {                       // W1: K=128, N=256
        int n = o / D_IN, k = o - n * D_IN;
        Wt1[o] = __float2bfloat16(W1[(size_t)k * H1 + n]);
    } else if (o < D_IN * H1 + H1 * H2) {      // W2: K=256, N=256
        int p = o - D_IN * H1;
        int n = p / H1, k = p - n * H1;
        Wt2[p] = __float2bfloat16(W2[(size_t)k * H2 + n]);
    } else {                                   // W3: K=256, N=128
        int p = o - D_IN * H1 - H1 * H2;
        int n = p / H2, k = p - n * H2;
        Wt3[p] = __float2bfloat16(W3[(size_t)k * D_OUT + n]);
    }
}

// ---------------------------------------------------------------------------
// Fused per-group pipeline: one block per group, 256 threads (4 waves).
// Chunk of up to 64 members at a time; carries (per-column prefix state)
// live in registers. Stages per chunk:
//   scan1 (x -> A1, LDS S3)                        [threads 0..127 = cols]
//   MFMA  h1 = relu(A1 @ Wt1^T + b1)  -> S1        [all 4 waves]
//   scan2 (h1 -> A2, LDS S2)                       [256 cols]
//   MFMA  h2 = relu(A2 @ Wt2^T + b2)  -> S1
//   MFMA  P  = h2 @ Wt3^T             -> S3
//   scan3 (P -> relu(agg + b3), fp32) -> S4 (=S2)  [128 cols]
//   LayerNorm rows -> out (global)
// Rows >= mt carry sd=0 so scans run fixed 64 iters and zero dead rows.
// LDS strides multiples of 8 shorts keep ds_read_b128 16B-aligned; the
// 264/136 strides rotate banks by 4/row (<=4-way aliasing on column scans).
// ---------------------------------------------------------------------------

#define S1K 264   // h1/h2 buffer stride (bf16), C=256
#define S2K 264   // A2 buffer stride (bf16)
#define S3K 136   // A1/P buffer stride (bf16), C=128
#define S4K 132   // fp32 out stride (aliases S2)

__global__ __launch_bounds__(256) void fused_gcn(
    const float* __restrict__ x,
    const __hip_bfloat16* __restrict__ Wt1,
    const __hip_bfloat16* __restrict__ Wt2,
    const __hip_bfloat16* __restrict__ Wt3,
    const float* __restrict__ b1, const float* __restrict__ b2,
    const float* __restrict__ b3,
    const float* __restrict__ gamma, const float* __restrict__ beta,
    const float* __restrict__ dis, const int* __restrict__ perm,
    const int* __restrict__ gs,
    float* __restrict__ out)
{
    __shared__ short S1[64 * S1K];
    __shared__ short S2[64 * S2K];
    __shared__ short S3[64 * S3K];
    __shared__ int   sp[64];
    __shared__ float sd[64];
    float* S4 = (float*)S2;   // aliased: A2 dead before scan3 writes

    int tid = threadIdx.x;
    int wave = tid >> 6;
    int lane = tid & 63;
    int quad = lane >> 4;
    int l15 = lane & 15;

    int g = blockIdx.x;
    int s = gs[g], cnt = gs[g + 1] - s;
    if (cnt <= 0) return;

    // hoisted per-thread constants
    float bj1[4], bj2[4];
    {
        int nw = wave * 64;
#pragma unroll
        for (int j = 0; j < 4; ++j) {
            bj1[j] = b1[nw + j * 16 + l15];
            bj2[j] = b2[nw + j * 16 + l15];
        }
    }
    float b3v = (tid < 128) ? b3[tid] : 0.0f;
    float2 gmv = *(const float2*)&gamma[lane * 2];
    float2 btv = *(const float2*)&beta[lane * 2];

    float carry1 = 0.0f, carry2 = 0.0f, carry3 = 0.0f;

    for (int base = 0; base < cnt; base += 64) {
        int mt = min(64, cnt - base);
        __syncthreads();   // prev chunk's LN readers done with sp/S4
        if (tid < 64) {
            int p = (tid < mt) ? perm[s + base + tid] : perm[s];
            sp[tid] = p;
            sd[tid] = (tid < mt) ? dis[p] : 0.0f;
        }
        __syncthreads();

        // ---- scan1: A1 = dis * (carry1 + cumsum(x*dis)) -> S3 bf16 ----
        if (tid < 128) {
            int c = tid;
            float acc = carry1;
#pragma unroll
            for (int rb = 0; rb < 64; rb += 32) {
                float v[32];
#pragma unroll
                for (int q = 0; q < 32; ++q)
                    v[q] = x[(size_t)sp[rb + q] * D_IN + c];
#pragma unroll
                for (int q = 0; q < 32; ++q) {
                    float dn = sd[rb + q];
                    acc += v[q] * dn;
                    S3[(rb + q) * S3K + c] = f2b(acc * dn);
                }
            }
            carry1 = acc;
        }
        __syncthreads();

        // ---- stage2: h1 = relu(A1 @ Wt1^T + b1) -> S1 ----
        {
            floatx4 acc[4][4];
#pragma unroll
            for (int i = 0; i < 4; ++i)
#pragma unroll
                for (int j = 0; j < 4; ++j) acc[i][j] = (floatx4)0.0f;
            int nw = wave * 64;
#pragma unroll
            for (int kk = 0; kk < D_IN; kk += 32) {
                short8 af[4], bf[4];
#pragma unroll
                for (int i = 0; i < 4; ++i)
                    af[i] = *(const short8*)&S3[(i * 16 + l15) * S3K + kk + quad * 8];
#pragma unroll
                for (int j = 0; j < 4; ++j)
                    bf[j] = *(const short8*)((const short*)Wt1 +
                            (size_t)(nw + j * 16 + l15) * D_IN + kk + quad * 8);
#pragma unroll
                for (int i = 0; i < 4; ++i)
#pragma unroll
                    for (int j = 0; j < 4; ++j)
                        acc[i][j] = __builtin_amdgcn_mfma_f32_16x16x32_bf16(
                            af[i], bf[j], acc[i][j], 0, 0, 0);
            }
#pragma unroll
            for (int i = 0; i < 4; ++i)
#pragma unroll
                for (int j = 0; j < 4; ++j)
#pragma unroll
                    for (int r = 0; r < 4; ++r) {
                        int row = i * 16 + quad * 4 + r;
                        S1[row * S1K + nw + j * 16 + l15] =
                            f2b(fmaxf(acc[i][j][r] + bj1[j], 0.0f));
                    }
        }
        __syncthreads();

        // ---- scan2: A2 = dis * (carry2 + cumsum(h1*dis)) -> S2 bf16 ----
        {
            int c = tid;   // 256 cols
            float acc = carry2;
#pragma unroll
            for (int rb = 0; rb < 64; rb += 16) {
                float v[16];
#pragma unroll
                for (int q = 0; q < 16; ++q)
                    v[q] = b2f(S1[(rb + q) * S1K + c]);
#pragma unroll
                for (int q = 0; q < 16; ++q) {
                    float dn = sd[rb + q];
                    acc += v[q] * dn;
                    S2[(rb + q) * S2K + c] = f2b(acc * dn);
                }
            }
            carry2 = acc;
        }
        __syncthreads();

        // ---- stage4: h2 = relu(A2 @ Wt2^T + b2) -> S1 ----
        {
            floatx4 acc[4][4];
#pragma unroll
            for (int i = 0; i < 4; ++i)
#pragma unroll
                for (int j = 0; j < 4; ++j) acc[i][j] = (floatx4)0.0f;
            int nw = wave * 64;
#pragma unroll
            for (int kk = 0; kk < H1; kk += 32) {
                short8 af[4], bf[4];
#pragma unroll
                for (int i = 0; i < 4; ++i)
                    af[i] = *(const short8*)&S2[(i * 16 + l15) * S2K + kk + quad * 8];
#pragma unroll
                for (int j = 0; j < 4; ++j)
                    bf[j] = *(const short8*)((const short*)Wt2 +
                            (size_t)(nw + j * 16 + l15) * H1 + kk + quad * 8);
#pragma unroll
                for (int i = 0; i < 4; ++i)
#pragma unroll
                    for (int j = 0; j < 4; ++j)
                        acc[i][j] = __builtin_amdgcn_mfma_f32_16x16x32_bf16(
                            af[i], bf[j], acc[i][j], 0, 0, 0);
            }
            __syncthreads();   // everyone's A2 reads done before S1 overwrite? NO:
            // S1 is the OUTPUT here (h1 dead after scan2). The barrier above
            // protects nothing for S1 but is needed before overwriting S1
            // while other waves might still be... all waves only READ S2 in
            // this stage; S1 reads ended at scan2 (barrier already passed).
#pragma unroll
            for (int i = 0; i < 4; ++i)
#pragma unroll
                for (int j = 0; j < 4; ++j)
#pragma unroll
                    for (int r = 0; r < 4; ++r) {
                        int row = i * 16 + quad * 4 + r;
                        S1[row * S1K + nw + j * 16 + l15] =
                            f2b(fmaxf(acc[i][j][r] + bj2[j], 0.0f));
                    }
        }
        __syncthreads();

        // ---- stage5: P = h2 @ Wt3^T -> S3 bf16 [64][128] ----
        {
            floatx4 acc[4][2];
#pragma unroll
            for (int i = 0; i < 4; ++i)
#pragma unroll
                for (int j = 0; j < 2; ++j) acc[i][j] = (floatx4)0.0f;
            int nw = wave * 32;
#pragma unroll
            for (int kk = 0; kk < H2; kk += 32) {
                short8 af[4], bf[2];
#pragma unroll
                for (int i = 0; i < 4; ++i)
                    af[i] = *(const short8*)&S1[(i * 16 + l15) * S1K + kk + quad * 8];
#pragma unroll
                for (int j = 0; j < 2; ++j)
                    bf[j] = *(const short8*)((const short*)Wt3 +
                            (size_t)(nw + j * 16 + l15) * H2 + kk + quad * 8);
#pragma unroll
                for (int i = 0; i < 4; ++i)
#pragma unroll
                    for (int j = 0; j < 2; ++j)
                        acc[i][j] = __builtin_amdgcn_mfma_f32_16x16x32_bf16(
                            af[i], bf[j], acc[i][j], 0, 0, 0);
            }
#pragma unroll
            for (int i = 0; i < 4; ++i)
#pragma unroll
                for (int j = 0; j < 2; ++j)
#pragma unroll
                    for (int r = 0; r < 4; ++r) {
                        int row = i * 16 + quad * 4 + r;
                        S3[row * S3K + nw + j * 16 + l15] = f2b(acc[i][j][r]);
                    }
        }
        __syncthreads();

        // ---- scan3: out = relu(dis*(carry3+cumsum(P*dis)) + b3) -> S4 fp32
        if (tid < 128) {
            int c = tid;
            float acc = carry3;
#pragma unroll
            for (int rb = 0; rb < 64; rb += 16) {
                float v[16];
#pragma unroll
                for (int q = 0; q < 16; ++q)
                    v[q] = b2f(S3[(rb + q) * S3K + c]);
#pragma unroll
                for (int q = 0; q < 16; ++q) {
                    float dn = sd[rb + q];
                    acc += v[q] * dn;
                    S4[(rb + q) * S4K + c] = fmaxf(acc * dn + b3v, 0.0f);
                }
            }
            carry3 = acc;
        }
        __syncthreads();

        // ---- LayerNorm rows -> out ----
        for (int r = wave; r < mt; r += 4) {
            float2 v = *(const float2*)&S4[r * S4K + lane * 2];
            float s1 = v.x + v.y;
            float s2v = v.x * v.x + v.y * v.y;
#pragma unroll
            for (int off = 32; off > 0; off >>= 1) {
                s1 += __shfl_down(s1, off);
                s2v += __shfl_down(s2v, off);
            }
            s1 = __shfl(s1, 0);
            s2v = __shfl(s2v, 0);
            float mu = s1 * (1.0f / D_OUT);
            float var = s2v * (1.0f / D_OUT) - mu * mu;
            float rstd = rsqrtf(var + 1e-5f);
            float2 o;
            o.x = (v.x - mu) * rstd * gmv.x + btv.x;
            o.y = (v.y - mu) * rstd * gmv.y + btv.y;
            *(float2*)&out[(size_t)sp[r] * D_OUT + lane * 2] = o;
        }
    }
}

// ---------------------------------------------------------------------------

extern "C" void kernel_launch(void* const* d_in, const int* in_sizes, int n_in,
                              void* d_out, int out_size, void* d_ws, size_t ws_size,
                              hipStream_t stream) {
    const float* x     = (const float*)d_in[0];
    const int*   idx   = (const int*)d_in[1];
    const float* W1    = (const float*)d_in[2];
    const float* b1    = (const float*)d_in[3];
    const float* W2    = (const float*)d_in[4];
    const float* b2    = (const float*)d_in[5];
    const float* W3    = (const float*)d_in[6];
    const float* b3    = (const float*)d_in[7];
    const float* gamma = (const float*)d_in[8];
    const float* beta  = (const float*)d_in[9];
    float* out = (float*)d_out;

    char* ws = (char*)d_ws;
    size_t off = 0;
    auto alloc = [&](size_t bytes) -> void* {
        void* p = (void*)(ws + off);
        off += (bytes + 255) & ~(size_t)255;
        return p;
    };
    float* dis   = (float*)alloc(NN * sizeof(float));
    int*   perm  = (int*)alloc(NN * sizeof(int));
    int*   lrank = (int*)alloc(NN * sizeof(int));
    int*   gs    = (int*)alloc((NG + 1) * sizeof(int));
    int*   bhist = (int*)alloc(NG * NB_PAD * sizeof(int));
    int*   boff  = (int*)alloc(NG * NB_PAD * sizeof(int));
    __hip_bfloat16* Wt1 = (__hip_bfloat16*)alloc((size_t)D_IN * H1 * 2);
    __hip_bfloat16* Wt2 = (__hip_bfloat16*)alloc((size_t)H1 * H2 * 2);
    __hip_bfloat16* Wt3 = (__hip_bfloat16*)alloc((size_t)H2 * D_OUT * 2);

    rank1_kernel<<<NB_RANK, 256, 0, stream>>>(idx, lrank, bhist, NN);
    rank2_kernel<<<1, 512, 0, stream>>>(bhist, boff, gs);
    rank3_kernel<<<NB_RANK, 256, 0, stream>>>(idx, lrank, boff, gs, dis, perm, NN);
    wt_all<<<(D_IN * H1 + H1 * H2 + H2 * D_OUT + 255) / 256, 256, 0, stream>>>(
        W1, W2, W3, Wt1, Wt2, Wt3);

    fused_gcn<<<NG, 256, 0, stream>>>(
        x, Wt1, Wt2, Wt3, b1, b2, b3, gamma, beta, dis, perm, gs, out);
}